// Round 10
// baseline (271.807 us; speedup 1.0000x reference)
//
#include <hip/hip_runtime.h>
#include <hip/hip_bf16.h>

#define L 401
#define D 128
#define BATCH 2
#define PADU 136   // ushorts per LDS row (128 + 8 pad)
#define PADB 272   // bytes per LDS row (16B-aligned, bank-step 4)

typedef __attribute__((ext_vector_type(8))) short short8;
typedef __attribute__((ext_vector_type(4))) float f32x4;

__device__ __forceinline__ ushort bf16_bits(float f) {
  __hip_bfloat16 h = __float2bfloat16(f);
  return *reinterpret_cast<ushort*>(&h);
}

// GELU, exact-erf flavor via A&S 7.1.25 3-term (|erf err| <= 2.5e-5)
__device__ __forceinline__ float gelu_fast(float v) {
  const float a = fabsf(v) * 0.70710678118654752f;
  const float t = __builtin_amdgcn_rcpf(fmaf(a, 0.47047f, 1.0f));
  float p = fmaf(t, 0.3739278f, -0.0479399f);
  p = fmaf(p, t, 0.1740121f);
  p = p * t;  // 0.5*(a1 t + a2 t^2 + a3 t^3)
  const float e = __builtin_amdgcn_exp2f(a * a * -1.4426950408889634f);
  const float q = p * e;  // 0.5*(1 - erf(a))
  const float cdf = (v < 0.f) ? q : 1.0f - q;
  return v * cdf;
}

// ---- XOR-swizzled 256B-row LDS helpers (gemm_tmp A-tile) ----
__device__ __forceinline__ short8 frag_read_swz(const char* lds, int row, int cb) {
  return *(const short8*)(lds + row * 256 + (cb ^ ((row & 7) << 4)));
}

__device__ __forceinline__ void stage_swz(char* lds, const __hip_bfloat16* src,
                                          int row0, int rowmax, int tid) {
#pragma unroll
  for (int it = 0; it < 4; ++it) {
    int r = it * 32 + (tid >> 4);
    int cb = (tid & 15) * 16;
    int sr = row0 + r;
    sr = sr > rowmax ? rowmax : sr;
    short8 v = *(const short8*)((const char*)src + (size_t)sr * 256 + cb);
    *(short8*)(lds + r * 256 + (cb ^ ((r & 7) << 4))) = v;
  }
}

// ---------------- kernel 1: prep (transpose W_bil + cast x + W1 fold) ----------------
__global__ void prep_kernel(const float* __restrict__ x, const float* __restrict__ W_bil,
                            const float* __restrict__ W1, const float* __restrict__ ln_g,
                            const float* __restrict__ ln_b, const float* __restrict__ b1,
                            __hip_bfloat16* __restrict__ xbf, __hip_bfloat16* __restrict__ wbt,
                            __hip_bfloat16* __restrict__ wgbf, float* __restrict__ s1,
                            float* __restrict__ s2b1) {
  __shared__ alignas(16) ushort t[128 * PADU];
  __shared__ float red[8];
  const int bid = blockIdx.x;
  const int tid = threadIdx.x;
  if (bid < 128) {
    // W_bil[bid][d][e] -> wbt[bid][e][d], with 8B XOR swizzle in LDS
    const float* in = W_bil + (size_t)bid * D * D;
#pragma unroll
    for (int it = 0; it < 16; ++it) {
      int idx = it * 256 + tid;
      int d = idx >> 5;
      int m = idx & 31;   // e-quad
      int e = m * 4;
      int swz = (m & 15) << 3;
      float4 f4 = ((const float4*)in)[idx];
      char* base = (char*)t;
      *(ushort*)(base + (size_t)(e + 0) * PADB + ((2 * d) ^ swz)) = bf16_bits(f4.x);
      *(ushort*)(base + (size_t)(e + 1) * PADB + ((2 * d) ^ swz)) = bf16_bits(f4.y);
      *(ushort*)(base + (size_t)(e + 2) * PADB + ((2 * d) ^ swz)) = bf16_bits(f4.z);
      *(ushort*)(base + (size_t)(e + 3) * PADB + ((2 * d) ^ swz)) = bf16_bits(f4.w);
    }
    __syncthreads();
    ushort* out = (ushort*)(wbt + (size_t)bid * D * D);
    const int e = tid >> 1;
    const int dh = (tid & 1) * 64;
    const int swz = ((e >> 2) & 15) << 3;
    const char* base = (const char*)t + (size_t)e * PADB;
#pragma unroll
    for (int c = 0; c < 16; ++c) {
      int d0 = dh + c * 4;
      unsigned long long v = *(const unsigned long long*)(base + ((2 * d0) ^ swz));
      *(unsigned long long*)&out[e * D + d0] = v;
    }
  } else if (bid < 154) {
    // cast x -> bf16, vectorized
    const int n4 = (BATCH * L * D) / 4;  // 25664
    int i4 = (bid - 128) * 1024 + tid;
#pragma unroll
    for (int c = 0; c < 4; ++c) {
      int idx = i4 + c * 256;
      if (idx < n4) {
        float4 f4 = ((const float4*)x)[idx];
        ushort4 o;
        o.x = bf16_bits(f4.x); o.y = bf16_bits(f4.y);
        o.z = bf16_bits(f4.z); o.w = bf16_bits(f4.w);
        ((ushort4*)xbf)[idx] = o;
      }
    }
  } else {
    // per-e: Wg = W1*g (bf16), s1[e] = sum Wg, s2b1[e] = sum W1*lnb + b1[e]
    const int e = bid - 154;
    float s1p = 0.f, s2p = 0.f;
    if (tid < 128) {
      const int d = tid;
      const float wv = W1[e * D + d];
      const float wg = wv * ln_g[d];
      wgbf[e * D + d] = __float2bfloat16(wg);
      s1p = wg;
      s2p = wv * ln_b[d];
    }
#pragma unroll
    for (int m = 1; m <= 32; m <<= 1) {
      s1p += __shfl_xor(s1p, m);
      s2p += __shfl_xor(s2p, m);
    }
    const int wv_ = tid >> 6;
    if ((tid & 63) == 0) { red[wv_ * 2] = s1p; red[wv_ * 2 + 1] = s2p; }
    __syncthreads();
    if (tid == 0) {
      s1[e] = red[0] + red[2] + red[4] + red[6];
      s2b1[e] = red[1] + red[3] + red[5] + red[7] + b1[e];
    }
  }
}

// ---------------- kernel 2: tmp[b,i,k,e] = sum_d x[b,i,d] * Wbt[k,e,d] ----------------
// Single-LDS-buffer version: only wbt[kt] staged (32 KB, swizzled). x B-frags read
// directly from global (L2-resident, 200 KB). Unconditional MFMAs; store guarded i<L.
__global__ __launch_bounds__(512, 6) void gemm_tmp(const __hip_bfloat16* __restrict__ xbf,
                                                   const __hip_bfloat16* __restrict__ wbt,
                                                   __hip_bfloat16* __restrict__ tmp) {
  __shared__ char ldsE[128 * 256];
  const int tid = threadIdx.x;
  const int lane = tid & 63;
  const int w = tid >> 6;     // 0..7
  const int c0 = lane & 15;
  const int lg = lane >> 4;
  const int kt = blockIdx.x;
  const int i0 = blockIdx.y * 128;
  const int b = blockIdx.z;

  stage_swz(ldsE, wbt + (size_t)kt * D * D, 0, 127, tid);

  // per-cf x row pointers (clamped; cndmask not a branch)
  const char* xbase = (const char*)(xbf + (size_t)b * L * D);
  const char* xrows[8];
#pragma unroll
  for (int cf = 0; cf < 8; ++cf) {
    int irow = i0 + cf * 16 + c0;
    irow = irow < L ? irow : (L - 1);
    xrows[cf] = xbase + (size_t)irow * 256;
  }
  __syncthreads();

  f32x4 acc[8];
#pragma unroll
  for (int cf = 0; cf < 8; ++cf) acc[cf] = (f32x4){0.f, 0.f, 0.f, 0.f};

#pragma unroll
  for (int ks = 0; ks < 4; ++ks) {
    const int cb = ks * 64 + lg * 16;
    short8 ae = frag_read_swz(ldsE, w * 16 + c0, cb);
#pragma unroll
    for (int cf = 0; cf < 8; ++cf) {
      short8 bi = *(const short8*)(xrows[cf] + lg * 16 + ks * 64);
      acc[cf] = __builtin_amdgcn_mfma_f32_16x16x32_bf16(ae, bi, acc[cf], 0, 0, 0);
    }
  }

  ushort* outp = (ushort*)tmp;
  const int e0 = w * 16 + lg * 4;
#pragma unroll
  for (int cf = 0; cf < 8; ++cf) {
    const int i = i0 + cf * 16 + c0;
    if (i < L) {
      uint lo = (uint)bf16_bits(acc[cf][0]) | ((uint)bf16_bits(acc[cf][1]) << 16);
      uint hi = (uint)bf16_bits(acc[cf][2]) | ((uint)bf16_bits(acc[cf][3]) << 16);
      uint2 v; v.x = lo; v.y = hi;
      *(uint2*)(outp + ((size_t)(b * L + i)) * (D * D) + kt * D + e0) = v;
    }
  }
}

// ---------------- kernel 3: fused pair -> (LN folded) -> Linear+GELU -> dot(w2) ----------------
// Single-LDS-buffer (34.8 KB): ldsT holds tmp_i for GEMM1, then p-hat (wave-private
// j-rows) for GEMM2. x rows (GEMM1 B) and Wg rows (GEMM2 A) read from global/L2.
// bar3 eliminated (p rows are wave-private). 512 thr, wave owns 16 j.
__global__ __launch_bounds__(512, 6) void fused_contact(
    const __hip_bfloat16* __restrict__ xbf, const __hip_bfloat16* __restrict__ tmp,
    const __hip_bfloat16* __restrict__ wgbf, const float* __restrict__ b_bil,
    const float* __restrict__ s1, const float* __restrict__ s2b1,
    const float* __restrict__ w2, const float* __restrict__ b2,
    float* __restrict__ cont) {
  __shared__ char ldsT[128 * PADB];
  const int tid = threadIdx.x;
  const int lane = tid & 63;
  const int w = tid >> 6;             // 0..7
  const int c0 = lane & 15;
  const int lg = lane >> 4;
  const int b = blockIdx.z;
  const int i = blockIdx.y;
  const int j0 = blockIdx.x * 128;
  const int jme = j0 + w * 16 + c0;
  const int jclamp = jme < L ? jme : (L - 1);
  const bool live = (j0 + w * 16) < L;  // wave-uniform

  // stage tmp_i into ldsT (pad-272 rows)
  {
    const char* tsrc = (const char*)(tmp + ((size_t)(b * L + i)) * (D * D));
#pragma unroll
    for (int it = 0; it < 4; ++it) {
      int r = it * 32 + (tid >> 4);
      int cb = (tid & 15) * 16;
      short8 v = *(const short8*)(tsrc + (size_t)r * 256 + cb);
      *(short8*)(ldsT + r * PADB + cb) = v;
    }
  }
  // x fragment loads issued before the barrier (latency hides under stage+bar)
  const char* xrow = (const char*)(xbf + ((size_t)b * L + jclamp) * D);
  short8 bxv[4];
#pragma unroll
  for (int ks = 0; ks < 4; ++ks) bxv[ks] = *(const short8*)(xrow + lg * 16 + ks * 64);
  __syncthreads();  // bar1

  float rs = 0.f, nm = 0.f;
  f32x4 acc1[8];
  if (live) {
#pragma unroll
    for (int kf = 0; kf < 8; ++kf) acc1[kf] = (f32x4){0.f, 0.f, 0.f, 0.f};
    // GEMM1: C'[k][j] = sum_e tmp_i[k][e] * x[j][e]
#pragma unroll
    for (int ks = 0; ks < 4; ++ks) {
      const int co = lg * 16 + ks * 64;
#pragma unroll
      for (int kf = 0; kf < 8; ++kf) {
        short8 at = *(const short8*)(ldsT + (kf * 16 + c0) * PADB + co);
        acc1[kf] = __builtin_amdgcn_mfma_f32_16x16x32_bf16(at, bxv[ks], acc1[kf], 0, 0, 0);
      }
    }
    // + b_bil, stats over k (lane owns full k-row of its j)
    float s = 0.f, q = 0.f;
#pragma unroll
    for (int kf = 0; kf < 8; ++kf) {
      const float4 bb = *(const float4*)&b_bil[kf * 16 + lg * 4];
      acc1[kf][0] += bb.x; acc1[kf][1] += bb.y;
      acc1[kf][2] += bb.z; acc1[kf][3] += bb.w;
#pragma unroll
      for (int r = 0; r < 4; ++r) {
        const float v = acc1[kf][r];
        s += v;
        q += v * v;
      }
    }
    s += __shfl_xor(s, 16); s += __shfl_xor(s, 32);
    q += __shfl_xor(q, 16); q += __shfl_xor(q, 32);
    const float m = s * (1.f / 128.f);
    const float var = q * (1.f / 128.f) - m * m;
    rs = __builtin_amdgcn_rsqf(var + 1e-5f);
    nm = -rs * m;
  }
  __syncthreads();  // bar2: all GEMM1 reads of ldsT done; safe to overwrite
  if (!live) return;  // no barriers after this point

  // write raw biased p-hat (bf16) into own j-row of ldsT: 8 x ds_write_b64
  {
    char* prow = ldsT + (w * 16 + c0) * PADB + lg * 8;
#pragma unroll
    for (int kf = 0; kf < 8; ++kf) {
      uint lo = (uint)bf16_bits(acc1[kf][0]) | ((uint)bf16_bits(acc1[kf][1]) << 16);
      uint hi = (uint)bf16_bits(acc1[kf][2]) | ((uint)bf16_bits(acc1[kf][3]) << 16);
      uint2 v; v.x = lo; v.y = hi;
      *(uint2*)(prow + kf * 32) = v;
    }
  }

  // GEMM2: C2[e][j] = sum_d Wg[e][d] * p[j][d]; Wg A-frags from global (L2-hit)
  f32x4 acc2[8];
#pragma unroll
  for (int ef = 0; ef < 8; ++ef) acc2[ef] = (f32x4){0.f, 0.f, 0.f, 0.f};
  const char* wgc = (const char*)wgbf;
#pragma unroll
  for (int ks = 0; ks < 4; ++ks) {
    const int co = lg * 16 + ks * 64;
    short8 bx2 = *(const short8*)(ldsT + (w * 16 + c0) * PADB + co);
#pragma unroll
    for (int ef = 0; ef < 8; ++ef) {
      short8 at = *(const short8*)(wgc + (size_t)(ef * 16 + c0) * 256 + co);
      acc2[ef] = __builtin_amdgcn_mfma_f32_16x16x32_bf16(at, bx2, acc2[ef], 0, 0, 0);
    }
  }

  // epilogue: h = rs*hraw + nm*s1[e] + s2b1[e]; GELU; dot w2 over e; 2-shfl reduce
  float part = 0.f;
#pragma unroll
  for (int ef = 0; ef < 8; ++ef) {
    const int e0 = ef * 16 + lg * 4;
    const float4 s1v = *(const float4*)&s1[e0];
    const float4 c2v = *(const float4*)&s2b1[e0];
    const float4 w2v = *(const float4*)&w2[e0];
    const float v0 = fmaf(acc2[ef][0], rs, fmaf(nm, s1v.x, c2v.x));
    const float v1 = fmaf(acc2[ef][1], rs, fmaf(nm, s1v.y, c2v.y));
    const float v2 = fmaf(acc2[ef][2], rs, fmaf(nm, s1v.z, c2v.z));
    const float v3 = fmaf(acc2[ef][3], rs, fmaf(nm, s1v.w, c2v.w));
    part += gelu_fast(v0) * w2v.x;
    part += gelu_fast(v1) * w2v.y;
    part += gelu_fast(v2) * w2v.z;
    part += gelu_fast(v3) * w2v.w;
  }
  part += __shfl_xor(part, 16);
  part += __shfl_xor(part, 32);
  if (lg == 0 && jme < L) {
    cont[((size_t)(b * L + i)) * L + jme] = part + b2[0];
  }
}

// ---------------- kernel 4: symmetrize ----------------
__global__ void sym_kernel(const float* __restrict__ c, float* __restrict__ out) {
  int idx = blockIdx.x * 256 + threadIdx.x;
  const int n = BATCH * L * L;
  if (idx >= n) return;
  int b = idx / (L * L);
  int r = idx - b * (L * L);
  int i = r / L;
  int j = r - i * L;
  out[idx] = 0.5f * (c[(size_t)b * L * L + (size_t)i * L + j] +
                     c[(size_t)b * L * L + (size_t)j * L + i]);
}

extern "C" void kernel_launch(void* const* d_in, const int* in_sizes, int n_in,
                              void* d_out, int out_size, void* d_ws, size_t ws_size,
                              hipStream_t stream) {
  const float* x     = (const float*)d_in[0];
  const float* W_bil = (const float*)d_in[1];
  const float* b_bil = (const float*)d_in[2];
  const float* ln_g  = (const float*)d_in[3];
  const float* ln_b  = (const float*)d_in[4];
  const float* W1    = (const float*)d_in[5];
  const float* b1    = (const float*)d_in[6];
  const float* w2    = (const float*)d_in[7];
  const float* b2    = (const float*)d_in[8];
  float* out = (float*)d_out;

  char* ws = (char*)d_ws;
  __hip_bfloat16* xbf  = (__hip_bfloat16*)(ws + 0);        // 205,312 B
  __hip_bfloat16* wgbf = (__hip_bfloat16*)(ws + 205312);   // 32,768 B
  float* s1            = (float*)(ws + 238080);            // 512 B
  float* s2b1          = (float*)(ws + 238592);            // 512 B
  __hip_bfloat16* wbt  = (__hip_bfloat16*)(ws + 239104);   // 4,194,304 B
  __hip_bfloat16* tmp  = (__hip_bfloat16*)(ws + 4433408);  // 26,279,936 B
  float* cont          = (float*)(ws + 30713344);          // 1,286,408 B

  prep_kernel<<<282, 256, 0, stream>>>(x, W_bil, W1, ln_g, ln_b, b1,
                                       xbf, wbt, wgbf, s1, s2b1);
  gemm_tmp<<<dim3(D, 4, BATCH), 512, 0, stream>>>(xbf, wbt, tmp);
  fused_contact<<<dim3(4, L, BATCH), 512, 0, stream>>>(xbf, tmp, wgbf, b_bil,
                                                       s1, s2b1, w2, b2, cont);
  sym_kernel<<<(BATCH * L * L + 255) / 256, 256, 0, stream>>>(cont, out);
}

// Round 11
// 160.177 us; speedup vs baseline: 1.6969x; 1.6969x over previous
//
#include <hip/hip_runtime.h>
#include <hip/hip_bf16.h>

#define L 401
#define D 128
#define BATCH 2
#define PADU 136   // ushorts per LDS row (128 + 8 pad)
#define PADB 272   // bytes per LDS row (16B-aligned, bank-step 4)

typedef __attribute__((ext_vector_type(8))) short short8;
typedef __attribute__((ext_vector_type(4))) float f32x4;

__device__ __forceinline__ ushort bf16_bits(float f) {
  __hip_bfloat16 h = __float2bfloat16(f);
  return *reinterpret_cast<ushort*>(&h);
}

// GELU, exact-erf flavor via A&S 7.1.25 3-term (|erf err| <= 2.5e-5)
__device__ __forceinline__ float gelu_fast(float v) {
  const float a = fabsf(v) * 0.70710678118654752f;
  const float t = __builtin_amdgcn_rcpf(fmaf(a, 0.47047f, 1.0f));
  float p = fmaf(t, 0.3739278f, -0.0479399f);
  p = fmaf(p, t, 0.1740121f);
  p = p * t;  // 0.5*(a1 t + a2 t^2 + a3 t^3)
  const float e = __builtin_amdgcn_exp2f(a * a * -1.4426950408889634f);
  const float q = p * e;  // 0.5*(1 - erf(a))
  const float cdf = (v < 0.f) ? q : 1.0f - q;
  return v * cdf;
}

// ---- XOR-swizzled 256B-row LDS helpers (gemm_tmp, proven rounds 3/6/7) ----
__device__ __forceinline__ short8 frag_read_swz(const char* lds, int row, int cb) {
  return *(const short8*)(lds + row * 256 + (cb ^ ((row & 7) << 4)));
}

__device__ __forceinline__ void stage_swz(char* lds, const __hip_bfloat16* src,
                                          int row0, int rowmax, int tid) {
#pragma unroll
  for (int it = 0; it < 4; ++it) {
    int r = it * 32 + (tid >> 4);
    int cb = (tid & 15) * 16;
    int sr = row0 + r;
    sr = sr > rowmax ? rowmax : sr;
    short8 v = *(const short8*)((const char*)src + (size_t)sr * 256 + cb);
    *(short8*)(lds + r * 256 + (cb ^ ((r & 7) << 4))) = v;
  }
}

// ---------------- kernel 1: prep (transpose W_bil + cast x + W1 fold) ----------------
__global__ void prep_kernel(const float* __restrict__ x, const float* __restrict__ W_bil,
                            const float* __restrict__ W1, const float* __restrict__ ln_g,
                            const float* __restrict__ ln_b, const float* __restrict__ b1,
                            __hip_bfloat16* __restrict__ xbf, __hip_bfloat16* __restrict__ wbt,
                            __hip_bfloat16* __restrict__ wgbf, float* __restrict__ s1,
                            float* __restrict__ s2b1) {
  __shared__ alignas(16) ushort t[128 * PADU];
  __shared__ float red[8];
  const int bid = blockIdx.x;
  const int tid = threadIdx.x;
  if (bid < 128) {
    // W_bil[bid][d][e] -> wbt[bid][e][d], with 8B XOR swizzle in LDS
    const float* in = W_bil + (size_t)bid * D * D;
#pragma unroll
    for (int it = 0; it < 16; ++it) {
      int idx = it * 256 + tid;
      int d = idx >> 5;
      int m = idx & 31;   // e-quad
      int e = m * 4;
      int swz = (m & 15) << 3;
      float4 f4 = ((const float4*)in)[idx];
      char* base = (char*)t;
      *(ushort*)(base + (size_t)(e + 0) * PADB + ((2 * d) ^ swz)) = bf16_bits(f4.x);
      *(ushort*)(base + (size_t)(e + 1) * PADB + ((2 * d) ^ swz)) = bf16_bits(f4.y);
      *(ushort*)(base + (size_t)(e + 2) * PADB + ((2 * d) ^ swz)) = bf16_bits(f4.z);
      *(ushort*)(base + (size_t)(e + 3) * PADB + ((2 * d) ^ swz)) = bf16_bits(f4.w);
    }
    __syncthreads();
    ushort* out = (ushort*)(wbt + (size_t)bid * D * D);
    const int e = tid >> 1;
    const int dh = (tid & 1) * 64;
    const int swz = ((e >> 2) & 15) << 3;
    const char* base = (const char*)t + (size_t)e * PADB;
#pragma unroll
    for (int c = 0; c < 16; ++c) {
      int d0 = dh + c * 4;
      unsigned long long v = *(const unsigned long long*)(base + ((2 * d0) ^ swz));
      *(unsigned long long*)&out[e * D + d0] = v;
    }
  } else if (bid < 154) {
    // cast x -> bf16, vectorized
    const int n4 = (BATCH * L * D) / 4;  // 25664
    int i4 = (bid - 128) * 1024 + tid;
#pragma unroll
    for (int c = 0; c < 4; ++c) {
      int idx = i4 + c * 256;
      if (idx < n4) {
        float4 f4 = ((const float4*)x)[idx];
        ushort4 o;
        o.x = bf16_bits(f4.x); o.y = bf16_bits(f4.y);
        o.z = bf16_bits(f4.z); o.w = bf16_bits(f4.w);
        ((ushort4*)xbf)[idx] = o;
      }
    }
  } else {
    // per-e: Wg = W1*g (bf16), s1[e] = sum Wg, s2b1[e] = sum W1*lnb + b1[e]
    const int e = bid - 154;
    float s1p = 0.f, s2p = 0.f;
    if (tid < 128) {
      const int d = tid;
      const float wv = W1[e * D + d];
      const float wg = wv * ln_g[d];
      wgbf[e * D + d] = __float2bfloat16(wg);
      s1p = wg;
      s2p = wv * ln_b[d];
    }
#pragma unroll
    for (int m = 1; m <= 32; m <<= 1) {
      s1p += __shfl_xor(s1p, m);
      s2p += __shfl_xor(s2p, m);
    }
    const int wv_ = tid >> 6;
    if ((tid & 63) == 0) { red[wv_ * 2] = s1p; red[wv_ * 2 + 1] = s2p; }
    __syncthreads();
    if (tid == 0) {
      s1[e] = red[0] + red[2] + red[4] + red[6];
      s2b1[e] = red[1] + red[3] + red[5] + red[7] + b1[e];
    }
  }
}

// ---------------- kernel 2: tmp[b,i,k,e] = sum_d x[b,i,d] * Wbt[k,e,d] ----------------
// Round-7 proven version: A = Wbt[kt] e-rows, B = x i-rows -> C[e][i];
// unconditional MFMAs, direct per-lane uint2 stores guarded only by i < L.
__global__ __launch_bounds__(512, 4) void gemm_tmp(const __hip_bfloat16* __restrict__ xbf,
                                                   const __hip_bfloat16* __restrict__ wbt,
                                                   __hip_bfloat16* __restrict__ tmp) {
  __shared__ char ldsE[128 * 256];
  __shared__ char ldsI[128 * 256];
  const int tid = threadIdx.x;
  const int lane = tid & 63;
  const int w = tid >> 6;     // 0..7
  const int c0 = lane & 15;
  const int lg = lane >> 4;
  const int kt = blockIdx.x;
  const int i0 = blockIdx.y * 128;
  const int b = blockIdx.z;

  stage_swz(ldsI, xbf + (size_t)b * L * D, i0, L - 1, tid);
  stage_swz(ldsE, wbt + (size_t)kt * D * D, 0, 127, tid);
  __syncthreads();

  f32x4 acc[8];
#pragma unroll
  for (int cf = 0; cf < 8; ++cf) acc[cf] = (f32x4){0.f, 0.f, 0.f, 0.f};

#pragma unroll
  for (int ks = 0; ks < 4; ++ks) {
    const int cb = ks * 64 + lg * 16;
    short8 ae = frag_read_swz(ldsE, w * 16 + c0, cb);
#pragma unroll
    for (int cf = 0; cf < 8; ++cf) {
      short8 bi = frag_read_swz(ldsI, cf * 16 + c0, cb);
      acc[cf] = __builtin_amdgcn_mfma_f32_16x16x32_bf16(ae, bi, acc[cf], 0, 0, 0);
    }
  }

  ushort* outp = (ushort*)tmp;
  const int e0 = w * 16 + lg * 4;
#pragma unroll
  for (int cf = 0; cf < 8; ++cf) {
    const int i = i0 + cf * 16 + c0;
    if (i < L) {
      uint lo = (uint)bf16_bits(acc[cf][0]) | ((uint)bf16_bits(acc[cf][1]) << 16);
      uint hi = (uint)bf16_bits(acc[cf][2]) | ((uint)bf16_bits(acc[cf][3]) << 16);
      uint2 v; v.x = lo; v.y = hi;
      *(uint2*)(outp + ((size_t)(b * L + i)) * (D * D) + kt * D + e0) = v;
    }
  }
}

// ---------------- kernel 3: fused pair -> (LN folded) -> Linear+GELU -> dot(w2) ----------------
// 512 thr, 8 waves; wave owns 16 j (lane owns one j, all 128 k).
// ldsT: tmp_i for GEMM1, then p-hat (wave-private rows). ldsW: Wg, staged once
// before bar1, stable all kernel. x j-row preloaded to regs (T14). 2 barriers.
__global__ __launch_bounds__(512, 4) void fused_contact(
    const __hip_bfloat16* __restrict__ xbf, const __hip_bfloat16* __restrict__ tmp,
    const __hip_bfloat16* __restrict__ wgbf, const float* __restrict__ b_bil,
    const float* __restrict__ s1, const float* __restrict__ s2b1,
    const float* __restrict__ w2, const float* __restrict__ b2,
    float* __restrict__ cont) {
  __shared__ char ldsT[128 * PADB];
  __shared__ char ldsW[128 * PADB];
  const int tid = threadIdx.x;
  const int lane = tid & 63;
  const int w = tid >> 6;             // 0..7
  const int c0 = lane & 15;
  const int lg = lane >> 4;
  const int b = blockIdx.z;
  const int i = blockIdx.y;
  const int j0 = blockIdx.x * 128;
  const int jme = j0 + w * 16 + c0;
  const int jclamp = jme < L ? jme : (L - 1);
  const bool live = (j0 + w * 16) < L;  // wave-uniform

  // stage tmp_i -> ldsT and Wg -> ldsW (pad-272 rows, 4 b128 writes each)
  {
    const char* tsrc = (const char*)(tmp + ((size_t)(b * L + i)) * (D * D));
    const char* wsrc = (const char*)wgbf;
    const int cb = (tid & 15) * 16;
#pragma unroll
    for (int it = 0; it < 4; ++it) {
      int r = it * 32 + (tid >> 4);
      *(short8*)(ldsT + r * PADB + cb) = *(const short8*)(tsrc + (size_t)r * 256 + cb);
      *(short8*)(ldsW + r * PADB + cb) = *(const short8*)(wsrc + (size_t)r * 256 + cb);
    }
  }
  // x j-row fragment preload (latency hides under staging + barrier)
  const char* xrow = (const char*)(xbf + ((size_t)b * L + jclamp) * D);
  short8 bxv[4];
#pragma unroll
  for (int ks = 0; ks < 4; ++ks) bxv[ks] = *(const short8*)(xrow + lg * 16 + ks * 64);
  __syncthreads();  // bar1

  float rs = 0.f, nm = 0.f;
  f32x4 acc1[8];
  if (live) {
#pragma unroll
    for (int kf = 0; kf < 8; ++kf) acc1[kf] = (f32x4){0.f, 0.f, 0.f, 0.f};
    // GEMM1: C'[k][j] = sum_e tmp_i[k][e] * x[j][e]
#pragma unroll
    for (int ks = 0; ks < 4; ++ks) {
      const int co = lg * 16 + ks * 64;
#pragma unroll
      for (int kf = 0; kf < 8; ++kf) {
        short8 at = *(const short8*)(ldsT + (kf * 16 + c0) * PADB + co);
        acc1[kf] = __builtin_amdgcn_mfma_f32_16x16x32_bf16(at, bxv[ks], acc1[kf], 0, 0, 0);
      }
    }
    // + b_bil, stats over k (lane owns full k-row of its j)
    float s = 0.f, q = 0.f;
#pragma unroll
    for (int kf = 0; kf < 8; ++kf) {
      const float4 bb = *(const float4*)&b_bil[kf * 16 + lg * 4];
      acc1[kf][0] += bb.x; acc1[kf][1] += bb.y;
      acc1[kf][2] += bb.z; acc1[kf][3] += bb.w;
#pragma unroll
      for (int r = 0; r < 4; ++r) {
        const float v = acc1[kf][r];
        s += v;
        q += v * v;
      }
    }
    s += __shfl_xor(s, 16); s += __shfl_xor(s, 32);
    q += __shfl_xor(q, 16); q += __shfl_xor(q, 32);
    const float m = s * (1.f / 128.f);
    const float var = q * (1.f / 128.f) - m * m;
    rs = __builtin_amdgcn_rsqf(var + 1e-5f);
    nm = -rs * m;
  }
  __syncthreads();  // bar2: all GEMM1 reads of ldsT done; safe to overwrite
  if (!live) return;  // no barriers below

  // write raw biased p-hat (bf16) into own j-row of ldsT (wave-private rows)
  {
    char* prow = ldsT + (w * 16 + c0) * PADB + lg * 8;
#pragma unroll
    for (int kf = 0; kf < 8; ++kf) {
      uint lo = (uint)bf16_bits(acc1[kf][0]) | ((uint)bf16_bits(acc1[kf][1]) << 16);
      uint hi = (uint)bf16_bits(acc1[kf][2]) | ((uint)bf16_bits(acc1[kf][3]) << 16);
      uint2 v; v.x = lo; v.y = hi;
      *(uint2*)(prow + kf * 32) = v;
    }
  }

  // GEMM2: C2[e][j] = sum_d Wg[e][d] * p[j][d]; A from ldsW (stable), B own p-row
  f32x4 acc2[8];
#pragma unroll
  for (int ef = 0; ef < 8; ++ef) acc2[ef] = (f32x4){0.f, 0.f, 0.f, 0.f};
#pragma unroll
  for (int ks = 0; ks < 4; ++ks) {
    const int co = lg * 16 + ks * 64;
    short8 bx2 = *(const short8*)(ldsT + (w * 16 + c0) * PADB + co);
#pragma unroll
    for (int ef = 0; ef < 8; ++ef) {
      short8 at = *(const short8*)(ldsW + (ef * 16 + c0) * PADB + co);
      acc2[ef] = __builtin_amdgcn_mfma_f32_16x16x32_bf16(at, bx2, acc2[ef], 0, 0, 0);
    }
  }

  // epilogue: h = rs*hraw + nm*s1[e] + s2b1[e]; GELU; dot w2 over e; 2-shfl reduce
  float part = 0.f;
#pragma unroll
  for (int ef = 0; ef < 8; ++ef) {
    const int e0 = ef * 16 + lg * 4;
    const float4 s1v = *(const float4*)&s1[e0];
    const float4 c2v = *(const float4*)&s2b1[e0];
    const float4 w2v = *(const float4*)&w2[e0];
    const float v0 = fmaf(acc2[ef][0], rs, fmaf(nm, s1v.x, c2v.x));
    const float v1 = fmaf(acc2[ef][1], rs, fmaf(nm, s1v.y, c2v.y));
    const float v2 = fmaf(acc2[ef][2], rs, fmaf(nm, s1v.z, c2v.z));
    const float v3 = fmaf(acc2[ef][3], rs, fmaf(nm, s1v.w, c2v.w));
    part += gelu_fast(v0) * w2v.x;
    part += gelu_fast(v1) * w2v.y;
    part += gelu_fast(v2) * w2v.z;
    part += gelu_fast(v3) * w2v.w;
  }
  part += __shfl_xor(part, 16);
  part += __shfl_xor(part, 32);
  if (lg == 0 && jme < L) {
    cont[((size_t)(b * L + i)) * L + jme] = part + b2[0];
  }
}

// ---------------- kernel 4: symmetrize ----------------
__global__ void sym_kernel(const float* __restrict__ c, float* __restrict__ out) {
  int idx = blockIdx.x * 256 + threadIdx.x;
  const int n = BATCH * L * L;
  if (idx >= n) return;
  int b = idx / (L * L);
  int r = idx - b * (L * L);
  int i = r / L;
  int j = r - i * L;
  out[idx] = 0.5f * (c[(size_t)b * L * L + (size_t)i * L + j] +
                     c[(size_t)b * L * L + (size_t)j * L + i]);
}

extern "C" void kernel_launch(void* const* d_in, const int* in_sizes, int n_in,
                              void* d_out, int out_size, void* d_ws, size_t ws_size,
                              hipStream_t stream) {
  const float* x     = (const float*)d_in[0];
  const float* W_bil = (const float*)d_in[1];
  const float* b_bil = (const float*)d_in[2];
  const float* ln_g  = (const float*)d_in[3];
  const float* ln_b  = (const float*)d_in[4];
  const float* W1    = (const float*)d_in[5];
  const float* b1    = (const float*)d_in[6];
  const float* w2    = (const float*)d_in[7];
  const float* b2    = (const float*)d_in[8];
  float* out = (float*)d_out;

  char* ws = (char*)d_ws;
  __hip_bfloat16* xbf  = (__hip_bfloat16*)(ws + 0);        // 205,312 B
  __hip_bfloat16* wgbf = (__hip_bfloat16*)(ws + 205312);   // 32,768 B
  float* s1            = (float*)(ws + 238080);            // 512 B
  float* s2b1          = (float*)(ws + 238592);            // 512 B
  __hip_bfloat16* wbt  = (__hip_bfloat16*)(ws + 239104);   // 4,194,304 B
  __hip_bfloat16* tmp  = (__hip_bfloat16*)(ws + 4433408);  // 26,279,936 B
  float* cont          = (float*)(ws + 30713344);          // 1,286,408 B

  prep_kernel<<<282, 256, 0, stream>>>(x, W_bil, W1, ln_g, ln_b, b1,
                                       xbf, wbt, wgbf, s1, s2b1);
  gemm_tmp<<<dim3(D, 4, BATCH), 512, 0, stream>>>(xbf, wbt, tmp);
  fused_contact<<<dim3(4, L, BATCH), 512, 0, stream>>>(xbf, tmp, wgbf, b_bil,
                                                       s1, s2b1, w2, b2, cont);
  sym_kernel<<<(BATCH * L * L + 255) / 256, 256, 0, stream>>>(cont, out);
}